// Round 2
// baseline (170.618 us; speedup 1.0000x reference)
//
#include <hip/hip_runtime.h>

#define BLOCK 256
#define SPLITS 16
#define QPT 8
#define PREPB 90
#define MAXC 136   // padded chunk capacity (m<=2048 -> cs=128); must be <= BLOCK

static_assert(MAXC <= BLOCK, "ballot-based gate count assumes <=1 staging iter/thread");

// d2(q,c) = q2 + (c2 - 2qx*cx - 2qy*cy); all terms integer-valued fp32 < 2^24
// for valid candidates -> exact. Sentinel (3e4): partial ~1.7e9 >> any valid
// d2 (<=5.3e5) -> never wins the cross-split min when gate>1. sqrt and x0.01
// are monotone roundings => min commutes through them; combine order is
// irrelevant for exactness (min is associative/commutative, values exact).

__device__ __forceinline__ float2 pk_fma2(float2 a, float2 b, float2 c) {
    return make_float2(fmaf(a.x, b.x, c.x), fmaf(a.y, b.y, c.y));
}
__device__ __forceinline__ float2 pk_mul2(float2 a, float2 b) {
    return make_float2(a.x * b.x, a.y * b.y);
}

// ---------- fallback path (only if ws too small; verified in round 0) ----------
__global__ __launch_bounds__(BLOCK) void prep_kernel(
    const float* __restrict__ pts, int m,
    int* __restrict__ gate, int* __restrict__ out_bits, int total)
{
    __shared__ int s_cnt;
    const int tid = blockIdx.x * BLOCK + threadIdx.x;
    const int n4 = total >> 2;
    const int4 iv = make_int4(0x7F7F7F7F, 0x7F7F7F7F, 0x7F7F7F7F, 0x7F7F7F7F);
    int4* o4 = (int4*)out_bits;
    for (int i = tid; i < n4; i += PREPB * BLOCK) o4[i] = iv;

    if (blockIdx.x == 0) {
        if (threadIdx.x == 0) s_cnt = 0;
        __syncthreads();
        int nv = 0;
        for (int i = threadIdx.x; i < m; i += BLOCK)
            nv += (fabsf(pts[i * 5 + 4]) > 0.1f) ? 1 : 0;
        if (nv) atomicAdd(&s_cnt, nv);
        __syncthreads();
        if (threadIdx.x == 0) *gate = (s_cnt > 1) ? 1 : 0;
    }
}

// ---------- single fused compute kernel (FUSED=true) or atomic fallback ----------
template<bool FUSED>
__global__ __launch_bounds__(BLOCK) void main_kernel(
    const int* __restrict__ li_coors, int n_li,
    const int* __restrict__ ra_coors, int n_ra,
    const float* __restrict__ pts,
    const int* __restrict__ vox,
    int m, int cs, int csPad,
    int* __restrict__ tickets,      // [qblocks], zeroed      (FUSED)
    int* __restrict__ gates,        // [qblocks], zeroed      (FUSED)
    float* __restrict__ part,       // [qblocks][SPLITS][BLOCK*QPT] (FUSED)
    float* __restrict__ out,        // final float output     (FUSED)
    const int* __restrict__ gate,   // fallback gate
    int* __restrict__ out_bits,     // fallback atomicMin output
    int total)
{
    __shared__ __align__(16) float sx[MAXC];
    __shared__ __align__(16) float sy[MAXC];
    __shared__ int s_ret;

    int g = 1;
    if (!FUSED) g = *gate;

    // Query decode first: scattered global loads overlap the staging below.
    const int li_total = n_li * 9;
    const int qbase = blockIdx.x * (BLOCK * QPT) + threadIdx.x;

    float n2x[QPT], n2y[QPT], q2[QPT], mn[QPT];
#pragma unroll
    for (int k = 0; k < QPT; ++k) {
        int q = qbase + k * BLOCK;
        float qx = 0.0f, qy = 0.0f;
        if (q < total) {
            const int shift_x[9] = {0,-1,1,0,-1,1,0,-1,1};
            const int shift_y[9] = {0, 0,0,1, 1,1,-1,-1,-1};
            int n, s;
            const int* src;
            if (q < li_total) { n = q / 9; s = q - n * 9; src = li_coors; }
            else { int r = q - li_total; n = r / 9; s = r - n * 9; src = ra_coors; }
            int cx = src[n * 2 + 0] + shift_x[s];
            int cy = src[n * 2 + 1] + shift_y[s];
            if (cx < 0) cx += 513;   // coords in [0,511], shift in {-1,0,1}
            if (cy < 0) cy += 513;
            qx = (float)cx; qy = (float)cy;
        }
        n2x[k] = -2.0f * qx;
        n2y[k] = -2.0f * qy;
        q2[k]  = fmaf(qx, qx, qy * qy);
        mn[k]  = 3.4e38f;
    }

    // Stage this split's candidate chunk (SoA; invalid/pad -> sentinel).
    // Each thread touches <=1 element (csPad <= MAXC <= BLOCK).
    const int base = blockIdx.y * cs;
    bool dyn = false;
    for (int i = threadIdx.x; i < csPad; i += BLOCK) {
        int gi = base + i;
        float x = 3.0e4f, y = 3.0e4f;
        if (i < cs && gi < m && fabsf(pts[gi * 5 + 4]) > 0.1f) {
            dyn = true;
            x = (float)vox[gi * 3 + 1];
            y = (float)vox[gi * 3 + 2];
        }
        sx[i] = x;
        sy[i] = y;
    }

    if (FUSED) {
        // Per-column dynamic-point count: this block's chunk contribution.
        // Column x receives all 16 chunks' counts => complete global count
        // exactly when all 16 of its blocks have passed the ticket below.
        unsigned long long b = __ballot(dyn);
        if ((threadIdx.x & 63) == 0 && b)
            atomicAdd(&gates[blockIdx.x], (int)__popcll(b));
    }
    __syncthreads();

    // 4 candidates/iter via 2x ds_read_b128; packed-pair fp32 math.
    const float4* __restrict__ X4 = (const float4*)sx;
    const float4* __restrict__ Y4 = (const float4*)sy;
    const int iters = csPad >> 2;
#pragma unroll 4
    for (int i = 0; i < iters; ++i) {
        float4 X = X4[i];
        float4 Y = Y4[i];
        float2 X01 = make_float2(X.x, X.y), X23 = make_float2(X.z, X.w);
        float2 Y01 = make_float2(Y.x, Y.y), Y23 = make_float2(Y.z, Y.w);
        float2 C01 = pk_fma2(X01, X01, pk_mul2(Y01, Y01));
        float2 C23 = pk_fma2(X23, X23, pk_mul2(Y23, Y23));
#pragma unroll
        for (int k = 0; k < QPT; ++k) {
            float2 nx = make_float2(n2x[k], n2x[k]);
            float2 ny = make_float2(n2y[k], n2y[k]);
            float2 T01 = pk_fma2(X01, nx, pk_fma2(Y01, ny, C01));
            float2 T23 = pk_fma2(X23, nx, pk_fma2(Y23, ny, C23));
            mn[k] = fminf(fminf(T01.x, T01.y), mn[k]);   // v_min3
            mn[k] = fminf(fminf(T23.x, T23.y), mn[k]);   // v_min3
        }
    }

    if (FUSED) {
        // Plain coalesced partial stores; no atomics, no sentinel init.
        float* __restrict__ dst =
            part + ((size_t)blockIdx.x * SPLITS + blockIdx.y) * (BLOCK * QPT);
#pragma unroll
        for (int k = 0; k < QPT; ++k)
            dst[k * BLOCK + threadIdx.x] = q2[k] + mn[k];

        // Release our stores + gate add, then take a ticket.
        __threadfence();
        if (threadIdx.x == 0)
            s_ret = atomicAdd(&tickets[blockIdx.x], 1);
        __syncthreads();

        if (s_ret == SPLITS - 1) {
            // Last block of this column: all 16 partials + gate are complete.
            __threadfence();   // acquire: invalidate so we see other XCDs' data
            const int gg = gates[blockIdx.x];
            const float* __restrict__ colp =
                part + (size_t)blockIdx.x * SPLITS * (BLOCK * QPT);
#pragma unroll
            for (int k = 0; k < QPT; ++k) {
                float v = q2[k] + mn[k];   // seed with own partial (registers)
#pragma unroll 4
                for (int y = 0; y < SPLITS; ++y)
                    v = fminf(v, colp[y * (BLOCK * QPT) + k * BLOCK + threadIdx.x]);
                int q = qbase + k * BLOCK;
                if (q < total)
                    out[q] = (gg > 1) ? sqrtf(fmaxf(v, 0.0f)) * 0.01f : 0.0f;
            }
        }
    } else {
#pragma unroll
        for (int k = 0; k < QPT; ++k) {
            int q = qbase + k * BLOCK;
            if (q < total) {
                float val = g ? sqrtf(q2[k] + mn[k]) * 0.01f : 0.0f;
                atomicMin(out_bits + q, __float_as_int(val));
            }
        }
    }
}

extern "C" void kernel_launch(void* const* d_in, const int* in_sizes, int n_in,
                              void* d_out, int out_size, void* d_ws, size_t ws_size,
                              hipStream_t stream) {
    const int*   li  = (const int*)d_in[0];
    const int*   ra  = (const int*)d_in[1];
    const float* pts = (const float*)d_in[2];
    const int*   vox = (const int*)d_in[3];

    const int n_li = in_sizes[0] / 2;
    const int n_ra = in_sizes[1] / 2;
    const int m    = in_sizes[2] / 5;

    const int total = (n_li + n_ra) * 9;                            // 92160
    const int qblocks = (total + BLOCK * QPT - 1) / (BLOCK * QPT);  // 45

    const int cs    = (m + SPLITS - 1) / SPLITS;                    // 128
    const int csPad = (cs + 3) & ~3;                                // <= MAXC

    // ws layout (FUSED): [tickets qblocks ints][gates qblocks ints][pad]
    //                    [part: qblocks*SPLITS*BLOCK*QPT floats @ +2048 floats]
    const size_t partOffF = 2048;
    const size_t need =
        (partOffF + (size_t)qblocks * SPLITS * (BLOCK * QPT)) * sizeof(float);

    if (ws_size >= need && 2 * qblocks <= (int)partOffF && csPad <= MAXC) {
        int*   tickets = (int*)d_ws;
        int*   gates   = tickets + qblocks;
        float* part    = (float*)d_ws + partOffF;
        float* out     = (float*)d_out;

        hipMemsetAsync(d_ws, 0, 2 * qblocks * sizeof(int), stream);
        main_kernel<true><<<dim3(qblocks, SPLITS), BLOCK, 0, stream>>>(
            li, n_li, ra, n_ra, pts, vox, m, cs, csPad,
            tickets, gates, part, out, nullptr, nullptr, total);
    } else {
        // Verified fallback: sentinel-init + gate, then atomicMin combine.
        int* gate = (int*)d_ws;
        int* outb = (int*)d_out;
        prep_kernel<<<PREPB, BLOCK, 0, stream>>>(pts, m, gate, outb, total);
        main_kernel<false><<<dim3(qblocks, SPLITS), BLOCK, 0, stream>>>(
            li, n_li, ra, n_ra, pts, vox, m, cs, csPad,
            nullptr, nullptr, nullptr, nullptr, gate, outb, total);
    }
}

// Round 3
// 88.525 us; speedup vs baseline: 1.9273x; 1.9273x over previous
//
#include <hip/hip_runtime.h>

#define BLOCK 192   // 3 waves/block; 92160 queries / 192 = 480 blocks exactly
#define MAXM  2048  // per-chunk candidate capacity (m = 2048 -> single chunk)

// d2(q,c) = q2 + (c2 - 2qx*cx - 2qy*cy). All intermediates are integer-valued
// fp32 with magnitude < 2^24 for valid candidates -> every fma/add is exact,
// so any association matches the reference's a2 + b2 - 2ab exactly.
// Sentinel (x=y=3e4): partial = c2 - 2qx*cx - 2qy*cy ~ 1.74e9, far above the
// max valid partial (~1.05e6) -> never wins the min when >=1 valid candidate
// exists (gate>1 guarantees >=2). sqrt and *0.01 are monotone roundings, so
// min commutes through them. This formula is bit-identical to the round-0/1
// kernels that passed with absmax=0.

__device__ __forceinline__ float2 pk_fma2(float2 a, float2 b, float2 c) {
    return make_float2(fmaf(a.x, b.x, c.x), fmaf(a.y, b.y, c.y));
}

__global__ __launch_bounds__(BLOCK) void gauss_kernel(
    const int* __restrict__ li_coors, int n_li,
    const int* __restrict__ ra_coors, int n_ra,
    const float* __restrict__ pts,
    const int* __restrict__ vox,
    int m,
    float* __restrict__ out, int total)
{
    __shared__ __align__(16) float sx[MAXM];
    __shared__ __align__(16) float sy[MAXM];
    __shared__ __align__(16) float sc[MAXM];   // c2 = x*x + y*y, staged once
    __shared__ int s_cnt;

    if (threadIdx.x == 0) s_cnt = 0;

    // ---- query decode: one query per thread; scattered loads issue early ----
    const int q = blockIdx.x * BLOCK + threadIdx.x;
    const bool valid = q < total;
    float nx = 0.0f, ny = 0.0f, q2 = 0.0f;
    if (valid) {
        const int shift_x[9] = {0,-1,1,0,-1,1,0,-1,1};
        const int shift_y[9] = {0, 0,0,1, 1,1,-1,-1,-1};
        const int li_total = n_li * 9;
        int n, s;
        const int* src;
        if (q < li_total) { n = q / 9; s = q - n * 9; src = li_coors; }
        else { int r = q - li_total; n = r / 9; s = r - n * 9; src = ra_coors; }
        int cx = src[n * 2 + 0] + shift_x[s];
        int cy = src[n * 2 + 1] + shift_y[s];
        if (cx < 0) cx += 513;   // coords in [0,511], shift in {-1,0,1}
        if (cy < 0) cy += 513;
        float qx = (float)cx, qy = (float)cy;
        nx = -2.0f * qx;
        ny = -2.0f * qy;
        q2 = fmaf(qx, qx, qy * qy);
    }

    float mn = 3.4e38f;
    int nv = 0;   // this block's full count of dynamic points (gate)

    for (int base = 0; base < m; base += MAXM) {   // single iteration at m=2048
        const int cs = min(m - base, MAXM);
        const int csPad = (cs + 3) & ~3;

        __syncthreads();   // (re)stage: prior chunk's readers done; s_cnt=0 visible
        for (int i = threadIdx.x; i < csPad; i += BLOCK) {
            int gi = base + i;
            float x = 3.0e4f, y = 3.0e4f;
            if (i < cs && fabsf(pts[gi * 5 + 4]) > 0.1f) {
                ++nv;
                x = (float)vox[gi * 3 + 1];
                y = (float)vox[gi * 3 + 2];
            }
            sx[i] = x;
            sy[i] = y;
            sc[i] = fmaf(x, x, y * y);
        }
        __syncthreads();

        // 4 candidates/iter: 3x ds_read_b128 (wave-broadcast, conflict-free)
        // + 4 pk_fma + 2 min3. c2 precomputed -> no per-quad C recompute.
        const float4* __restrict__ X4 = (const float4*)sx;
        const float4* __restrict__ Y4 = (const float4*)sy;
        const float4* __restrict__ C4 = (const float4*)sc;
        const float2 nx2 = make_float2(nx, nx);
        const float2 ny2 = make_float2(ny, ny);
        const int iters = csPad >> 2;
#pragma unroll 4
        for (int i = 0; i < iters; ++i) {
            float4 X = X4[i];
            float4 Y = Y4[i];
            float4 C = C4[i];
            float2 T01 = pk_fma2(make_float2(X.x, X.y), nx2,
                          pk_fma2(make_float2(Y.x, Y.y), ny2,
                                  make_float2(C.x, C.y)));
            float2 T23 = pk_fma2(make_float2(X.z, X.w), nx2,
                          pk_fma2(make_float2(Y.z, Y.w), ny2,
                                  make_float2(C.z, C.w)));
            mn = fminf(fminf(T01.x, T01.y), mn);   // v_min3
            mn = fminf(fminf(T23.x, T23.y), mn);   // v_min3
        }
    }

    // Block-local gate: every block staged ALL m points, so its own count is
    // the exact global count. No cross-block communication needed.
    if (nv) atomicAdd(&s_cnt, nv);
    __syncthreads();
    const int g = s_cnt;

    if (valid)
        out[q] = (g > 1) ? sqrtf(fmaxf(q2 + mn, 0.0f)) * 0.01f : 0.0f;
}

extern "C" void kernel_launch(void* const* d_in, const int* in_sizes, int n_in,
                              void* d_out, int out_size, void* d_ws, size_t ws_size,
                              hipStream_t stream) {
    const int*   li  = (const int*)d_in[0];
    const int*   ra  = (const int*)d_in[1];
    const float* pts = (const float*)d_in[2];
    const int*   vox = (const int*)d_in[3];

    const int n_li = in_sizes[0] / 2;
    const int n_ra = in_sizes[1] / 2;
    const int m    = in_sizes[2] / 5;

    const int total  = (n_li + n_ra) * 9;              // 92160
    const int blocks = (total + BLOCK - 1) / BLOCK;    // 480

    gauss_kernel<<<blocks, BLOCK, 0, stream>>>(
        li, n_li, ra, n_ra, pts, vox, m, (float*)d_out, total);
}

// Round 4
// 75.242 us; speedup vs baseline: 2.2676x; 1.1765x over previous
//
#include <hip/hip_runtime.h>

#define NW    16               // waves per block (candidate-split dimension)
#define BLOCK (NW * 64)        // 1024 threads
#define QPT   8                // queries per thread
#define QPB   (64 * QPT)       // 512 queries per block (same set in all waves)
#define MAXM  2048             // staged candidate chunk capacity

// d2(q,c) = q2 + (C - 2qx*cx - 2qy*cy), C = cx^2 + cy^2. All intermediates
// for valid candidates are integer-valued fp32 < 2^24 -> every fma/mul/add is
// exact, so any association matches the reference's a2 + b2 - 2ab exactly
// (verified absmax=0 in rounds 0-3). Sentinel (x=y=3e4): partial ~1.74e9 >>
// max valid partial (~1.05e6) -> never wins the min when gate>1 (>=2 valid
// candidates exist). sqrt and *0.01 are monotone roundings -> min commutes.

__device__ __forceinline__ float2 pk_fma2(float2 a, float2 b, float2 c) {
    return make_float2(fmaf(a.x, b.x, c.x), fmaf(a.y, b.y, c.y));
}
__device__ __forceinline__ float2 pk_mul2(float2 a, float2 b) {
    return make_float2(a.x * b.x, a.y * b.y);
}

__global__ __launch_bounds__(BLOCK) void gauss_kernel(
    const int* __restrict__ li_coors, int n_li,
    const int* __restrict__ ra_coors, int n_ra,
    const float* __restrict__ pts,
    const int* __restrict__ vox,
    int m,
    float* __restrict__ out, int total)
{
    __shared__ __align__(16) float sx[MAXM];          // 8 KB
    __shared__ __align__(16) float sy[MAXM];          // 8 KB
    __shared__ __align__(16) float part[NW * QPB];    // 32 KB: [wave][qslot]
    __shared__ float q2s[QPB];                        // 2 KB
    __shared__ int s_cnt;

    const int tid  = threadIdx.x;
    const int lane = tid & 63;
    const int w    = tid >> 6;

    if (tid == 0) s_cnt = 0;

    // ---- decode QPT queries; identical set across all 16 waves ----
    // q(k) = qbase + lane + 64*k  (consecutive lanes -> coalesced decode/out)
    const int qbase = blockIdx.x * QPB;
    const int li_total = n_li * 9;
    float nx[QPT], ny[QPT], q2[QPT], mn[QPT];
#pragma unroll
    for (int k = 0; k < QPT; ++k) {
        int q = qbase + lane + 64 * k;
        float qx = 0.0f, qy = 0.0f;
        if (q < total) {
            const int shift_x[9] = {0,-1,1,0,-1,1,0,-1,1};
            const int shift_y[9] = {0, 0,0,1, 1,1,-1,-1,-1};
            int n, s;
            const int* src;
            if (q < li_total) { n = q / 9; s = q - n * 9; src = li_coors; }
            else { int r = q - li_total; n = r / 9; s = r - n * 9; src = ra_coors; }
            int cx = src[n * 2 + 0] + shift_x[s];
            int cy = src[n * 2 + 1] + shift_y[s];
            if (cx < 0) cx += 513;   // coords in [0,511], shift in {-1,0,1}
            if (cy < 0) cy += 513;
            qx = (float)cx; qy = (float)cy;
        }
        nx[k] = -2.0f * qx;
        ny[k] = -2.0f * qy;
        q2[k] = fmaf(qx, qx, qy * qy);
        mn[k] = 3.4e38f;
    }

    // ---- candidate chunks: stage all m into LDS; each wave scans 1/NW ----
    for (int base = 0; base < m; base += MAXM) {
        const int cs  = min(m - base, MAXM);
        int per = (cs + NW - 1) / NW;
        per = (per + 3) & ~3;            // per-wave slice, multiple of 4 (<=128)
        const int tot = NW * per;        // <= MAXM

        __syncthreads();   // first iter: s_cnt init visible; later: readers done
        for (int i = tid; i < tot; i += BLOCK) {
            int gi = base + i;
            float x = 3.0e4f, y = 3.0e4f;
            bool dyn = false;
            if (i < cs && fabsf(pts[gi * 5 + 4]) > 0.1f) {
                dyn = true;
                x = (float)vox[gi * 3 + 1];
                y = (float)vox[gi * 3 + 2];
            }
            sx[i] = x;
            sy[i] = y;
            // exact global dynamic-point count, accumulated block-locally
            unsigned long long b = __ballot(dyn);
            if (lane == 0 && b) atomicAdd(&s_cnt, (int)__popcll(b));
        }
        __syncthreads();

        // wave w scans slice [w*per, (w+1)*per): 2x ds_read_b128 per 4 cands
        // (broadcast, conflict-free); C recomputed per quad (amortized /QPT).
        const float4* __restrict__ X4 = (const float4*)sx + ((w * per) >> 2);
        const float4* __restrict__ Y4 = (const float4*)sy + ((w * per) >> 2);
        const int iters = per >> 2;
#pragma unroll 4
        for (int i = 0; i < iters; ++i) {
            float4 X = X4[i];
            float4 Y = Y4[i];
            float2 X01 = make_float2(X.x, X.y), X23 = make_float2(X.z, X.w);
            float2 Y01 = make_float2(Y.x, Y.y), Y23 = make_float2(Y.z, Y.w);
            float2 C01 = pk_fma2(X01, X01, pk_mul2(Y01, Y01));
            float2 C23 = pk_fma2(X23, X23, pk_mul2(Y23, Y23));
#pragma unroll
            for (int k = 0; k < QPT; ++k) {
                float2 nx2 = make_float2(nx[k], nx[k]);
                float2 ny2 = make_float2(ny[k], ny[k]);
                float2 T01 = pk_fma2(X01, nx2, pk_fma2(Y01, ny2, C01));
                float2 T23 = pk_fma2(X23, nx2, pk_fma2(Y23, ny2, C23));
                mn[k] = fminf(fminf(T01.x, T01.y), mn[k]);   // v_min3
                mn[k] = fminf(fminf(T23.x, T23.y), mn[k]);   // v_min3
            }
        }
    }

    // ---- in-LDS combine across the 16 waves ----
    // part[w][qslot]: consecutive lanes -> consecutive banks (conflict-free)
#pragma unroll
    for (int k = 0; k < QPT; ++k)
        part[w * QPB + lane + 64 * k] = mn[k];
    if (w == 0) {
#pragma unroll
        for (int k = 0; k < QPT; ++k)
            q2s[lane + 64 * k] = q2[k];
    }
    __syncthreads();

    if (tid < QPB) {
        float v = 3.4e38f;
#pragma unroll
        for (int w2 = 0; w2 < NW; ++w2)
            v = fminf(v, part[w2 * QPB + tid]);
        int gq = qbase + tid;
        if (gq < total)
            out[gq] = (s_cnt > 1) ? sqrtf(fmaxf(q2s[tid] + v, 0.0f)) * 0.01f
                                  : 0.0f;
    }
}

extern "C" void kernel_launch(void* const* d_in, const int* in_sizes, int n_in,
                              void* d_out, int out_size, void* d_ws, size_t ws_size,
                              hipStream_t stream) {
    const int*   li  = (const int*)d_in[0];
    const int*   ra  = (const int*)d_in[1];
    const float* pts = (const float*)d_in[2];
    const int*   vox = (const int*)d_in[3];

    const int n_li = in_sizes[0] / 2;
    const int n_ra = in_sizes[1] / 2;
    const int m    = in_sizes[2] / 5;

    const int total  = (n_li + n_ra) * 9;            // 92160
    const int blocks = (total + QPB - 1) / QPB;      // 180

    gauss_kernel<<<blocks, BLOCK, 0, stream>>>(
        li, n_li, ra, n_ra, pts, vox, m, (float*)d_out, total);
}

// Round 5
// 73.740 us; speedup vs baseline: 2.3138x; 1.0204x over previous
//
#include <hip/hip_runtime.h>

#define NW    16               // waves per block (candidate-split dimension)
#define BLOCK (NW * 64)        // 1024 threads
#define QPT   6                // queries per thread
#define QPB   (64 * QPT)       // 384 queries per block -> 240 blocks (240 CUs)
#define MAXM  2048             // staged candidate chunk capacity

// d2(q,c) = q2 + (C - 2qx*cx - 2qy*cy), C = cx^2 + cy^2. All intermediates
// for valid candidates are integer-valued fp32 < 2^24 -> every fma/mul/add is
// exact, so any association matches the reference's a2 + b2 - 2ab exactly
// (verified absmax=0 in rounds 0-4). Sentinel (x=y=3e4): partial ~1.74e9 >>
// max valid partial (~1.05e6) -> never wins the min when gate>1 (>=2 valid
// candidates exist). sqrt and *0.01 are monotone roundings -> min commutes.
// Packed <2 x float> fma (v_pk_fma_f32) is per-lane IEEE fma -> bit-identical
// to the scalar version.

typedef float v2f __attribute__((ext_vector_type(2)));

__device__ __forceinline__ v2f pkfma(v2f a, v2f b, v2f c) {
    return __builtin_elementwise_fma(a, b, c);   // -> v_pk_fma_f32 on gfx950
}

__global__ __launch_bounds__(BLOCK) void gauss_kernel(
    const int* __restrict__ li_coors, int n_li,
    const int* __restrict__ ra_coors, int n_ra,
    const float* __restrict__ pts,
    const int* __restrict__ vox,
    int m,
    float* __restrict__ out, int total)
{
    __shared__ __align__(16) float sx[MAXM];          // 8 KB
    __shared__ __align__(16) float sy[MAXM];          // 8 KB
    __shared__ __align__(16) float part[NW * QPB];    // 24 KB: [wave][qslot]
    __shared__ float q2s[QPB];                        // 1.5 KB
    __shared__ int s_cnt;

    const int tid  = threadIdx.x;
    const int lane = tid & 63;
    const int w    = tid >> 6;

    if (tid == 0) s_cnt = 0;

    // ---- decode QPT queries; identical set across all 16 waves ----
    // q(k) = qbase + lane + 64*k  (consecutive lanes -> coalesced decode/out)
    const int qbase = blockIdx.x * QPB;
    const int li_total = n_li * 9;
    float nx[QPT], ny[QPT], q2[QPT], mn[QPT];
#pragma unroll
    for (int k = 0; k < QPT; ++k) {
        int q = qbase + lane + 64 * k;
        float qx = 0.0f, qy = 0.0f;
        if (q < total) {
            const int shift_x[9] = {0,-1,1,0,-1,1,0,-1,1};
            const int shift_y[9] = {0, 0,0,1, 1,1,-1,-1,-1};
            int n, s;
            const int* src;
            if (q < li_total) { n = q / 9; s = q - n * 9; src = li_coors; }
            else { int r = q - li_total; n = r / 9; s = r - n * 9; src = ra_coors; }
            int cx = src[n * 2 + 0] + shift_x[s];
            int cy = src[n * 2 + 1] + shift_y[s];
            if (cx < 0) cx += 513;   // coords in [0,511], shift in {-1,0,1}
            if (cy < 0) cy += 513;
            qx = (float)cx; qy = (float)cy;
        }
        nx[k] = -2.0f * qx;
        ny[k] = -2.0f * qy;
        q2[k] = fmaf(qx, qx, qy * qy);
        mn[k] = 3.4e38f;
    }

    // ---- candidate chunks: stage all m into LDS; each wave scans 1/NW ----
    for (int base = 0; base < m; base += MAXM) {
        const int cs  = min(m - base, MAXM);
        int per = (cs + NW - 1) / NW;
        per = (per + 3) & ~3;            // per-wave slice, multiple of 4 (<=128)
        const int tot = NW * per;        // <= MAXM

        __syncthreads();   // first iter: s_cnt init visible; later: readers done
        for (int i = tid; i < tot; i += BLOCK) {
            int gi = base + i;
            float x = 3.0e4f, y = 3.0e4f;
            bool dyn = false;
            if (i < cs && fabsf(pts[gi * 5 + 4]) > 0.1f) {
                dyn = true;
                x = (float)vox[gi * 3 + 1];
                y = (float)vox[gi * 3 + 2];
            }
            sx[i] = x;
            sy[i] = y;
            // exact global dynamic-point count, accumulated block-locally
            unsigned long long b = __ballot(dyn);
            if (lane == 0 && b) atomicAdd(&s_cnt, (int)__popcll(b));
        }
        __syncthreads();

        // wave w scans slice [w*per, (w+1)*per): 2x ds_read_b128 per 4 cands
        // (broadcast, conflict-free); packed-pair fp32 math (v_pk_fma_f32).
        const float4* __restrict__ X4 = (const float4*)sx + ((w * per) >> 2);
        const float4* __restrict__ Y4 = (const float4*)sy + ((w * per) >> 2);
        const int iters = per >> 2;
#pragma unroll 4
        for (int i = 0; i < iters; ++i) {
            float4 X = X4[i];
            float4 Y = Y4[i];
            v2f X01 = {X.x, X.y}, X23 = {X.z, X.w};
            v2f Y01 = {Y.x, Y.y}, Y23 = {Y.z, Y.w};
            v2f C01 = pkfma(X01, X01, Y01 * Y01);
            v2f C23 = pkfma(X23, X23, Y23 * Y23);
#pragma unroll
            for (int k = 0; k < QPT; ++k) {
                v2f nx2 = {nx[k], nx[k]};
                v2f ny2 = {ny[k], ny[k]};
                v2f T01 = pkfma(X01, nx2, pkfma(Y01, ny2, C01));
                v2f T23 = pkfma(X23, nx2, pkfma(Y23, ny2, C23));
                mn[k] = fminf(fminf(T01.x, T01.y), mn[k]);   // v_min3
                mn[k] = fminf(fminf(T23.x, T23.y), mn[k]);   // v_min3
            }
        }
    }

    // ---- in-LDS combine across the 16 waves ----
    // part[w][qslot]: consecutive lanes -> consecutive banks (conflict-free)
#pragma unroll
    for (int k = 0; k < QPT; ++k)
        part[w * QPB + lane + 64 * k] = mn[k];
    if (w == 0) {
#pragma unroll
        for (int k = 0; k < QPT; ++k)
            q2s[lane + 64 * k] = q2[k];
    }
    __syncthreads();

    if (tid < QPB) {
        float v = 3.4e38f;
#pragma unroll
        for (int w2 = 0; w2 < NW; ++w2)
            v = fminf(v, part[w2 * QPB + tid]);
        int gq = qbase + tid;
        if (gq < total)
            out[gq] = (s_cnt > 1) ? sqrtf(fmaxf(q2s[tid] + v, 0.0f)) * 0.01f
                                  : 0.0f;
    }
}

extern "C" void kernel_launch(void* const* d_in, const int* in_sizes, int n_in,
                              void* d_out, int out_size, void* d_ws, size_t ws_size,
                              hipStream_t stream) {
    const int*   li  = (const int*)d_in[0];
    const int*   ra  = (const int*)d_in[1];
    const float* pts = (const float*)d_in[2];
    const int*   vox = (const int*)d_in[3];

    const int n_li = in_sizes[0] / 2;
    const int n_ra = in_sizes[1] / 2;
    const int m    = in_sizes[2] / 5;

    const int total  = (n_li + n_ra) * 9;            // 92160
    const int blocks = (total + QPB - 1) / QPB;      // 240

    gauss_kernel<<<blocks, BLOCK, 0, stream>>>(
        li, n_li, ra, n_ra, pts, vox, m, (float*)d_out, total);
}